// Round 1
// baseline (525.069 us; speedup 1.0000x reference)
//
#include <hip/hip_runtime.h>
#include <hip/hip_bf16.h>
#include <cstdint>
#include <cstddef>

#define B_   2
#define N_   2048
#define D_   2048
#define H_   16
#define HD_  128
#define C_   128
#define NC_  16
#define M_   4096   // B_*N_

typedef __attribute__((ext_vector_type(8))) short bf16x8;
typedef __attribute__((ext_vector_type(4))) float f32x4;

__device__ __forceinline__ uint16_t f2bf(float f){
  __hip_bfloat16 h = __float2bfloat16(f);
  return *reinterpret_cast<uint16_t*>(&h);
}
__device__ __forceinline__ float bf2f(uint16_t u){
  union { uint32_t i; float f; } v; v.i = ((uint32_t)u) << 16; return v.f;
}

// async global->LDS, 16B per lane. LDS dest must be wave-uniform-base + lane*16.
__device__ __forceinline__ void async16(const uint16_t* g, uint16_t* l){
  __builtin_amdgcn_global_load_lds(
      (const __attribute__((address_space(1))) void*)g,
      (__attribute__((address_space(3))) void*)l, 16, 0, 0);
}

// XOR swizzle for [128][128] bf16 LDS tiles: row stride 256B aliases all
// 16 frag-lanes onto the same banks; swizzling 8-elem groups by row&15
// spreads them across 16 distinct 16B slots (<=2-way, free per m136).
__device__ __forceinline__ int swz(int row, int c){
  return row*128 + ((((c >> 3) ^ row) & 15) << 3) + (c & 7);
}

// ---------------------------------------------------------------- cast x
__global__ __launch_bounds__(256) void cast_kernel(
    const float* __restrict__ x, uint16_t* __restrict__ y)
{
  int i = (blockIdx.x*256 + threadIdx.x)*4;
  float4 f = *(const float4*)(x + i);
  ushort4 u;
  u.x = f2bf(f.x); u.y = f2bf(f.y); u.z = f2bf(f.z); u.w = f2bf(f.w);
  *(ushort4*)(y + i) = u;
}

// ------------------------------------------- transpose-cast W[R][Cc] -> Wt[Cc][R]
__global__ __launch_bounds__(256) void transpose_cast(
    const float* __restrict__ W, uint16_t* __restrict__ Wt, int R, int Cc)
{
  __shared__ uint16_t tile[32][33];
  const int tx = threadIdx.x & 31;
  const int ty = threadIdx.x >> 5;            // 0..7
  const int r0 = blockIdx.y*32, c0 = blockIdx.x*32;
  #pragma unroll
  for (int rr = 0; rr < 4; ++rr){
    int r = ty + rr*8;
    tile[r][tx] = f2bf(W[(size_t)(r0 + r)*Cc + c0 + tx]);
  }
  __syncthreads();
  #pragma unroll
  for (int rr = 0; rr < 4; ++rr){
    int r = ty + rr*8;                        // output row within tile = W column
    Wt[(size_t)(c0 + r)*R + r0 + tx] = tile[tx][r];
  }
}

// ------------------------------------------------------- m97-style GEMM (B^T)
// C[M][Ncols] = act(A[M][K] @ Bt[Ncols][K]^T). A,Bt bf16 row-major.
// ACT: 0 none, 1 silu, 2 sigmoid. OUTBF: 1 bf16 out, 0 fp32 out.
template<int ACT, int OUTBF>
__global__ __launch_bounds__(256)
void gemm_bt(const uint16_t* __restrict__ A, const uint16_t* __restrict__ Bt,
             void* __restrict__ Cout, int M, int Ncols, int K)
{
  __shared__ __align__(16) uint16_t As[128*32];
  __shared__ __align__(16) uint16_t Bs[128*32];
  const int t    = threadIdx.x;
  const int lane = t & 63, wave = t >> 6;
  const int wm = wave >> 1, wn = wave & 1;
  const int row0 = wm*64, col0 = wn*64;
  const int lr = lane & 15, kq = lane >> 4;

  const uint16_t* Ap = A  + (size_t)(blockIdx.y*128)*K;
  const uint16_t* Bp = Bt + (size_t)(blockIdx.x*128)*K;

  const f32x4 zero = {0.f, 0.f, 0.f, 0.f};
  f32x4 acc[4][4];
  #pragma unroll
  for (int i = 0; i < 4; ++i)
    #pragma unroll
    for (int j = 0; j < 4; ++j) acc[i][j] = zero;

  const int r0c = t >> 2;          // staging row for chunk c=t
  const int kc0 = (t & 3) * 8;     // staging k-offset (elements)

  for (int k0 = 0; k0 < K; k0 += 32){
    async16(Ap + (size_t)r0c*K      + k0 + kc0, As + t*8);
    async16(Ap + (size_t)(r0c+64)*K + k0 + kc0, As + (t+256)*8);
    async16(Bp + (size_t)r0c*K      + k0 + kc0, Bs + t*8);
    async16(Bp + (size_t)(r0c+64)*K + k0 + kc0, Bs + (t+256)*8);
    __syncthreads();
    bf16x8 af[4], bfr[4];
    #pragma unroll
    for (int i = 0; i < 4; ++i)
      af[i]  = *(const bf16x8*)(As + (row0 + i*16 + lr)*32 + kq*8);
    #pragma unroll
    for (int j = 0; j < 4; ++j)
      bfr[j] = *(const bf16x8*)(Bs + (col0 + j*16 + lr)*32 + kq*8);
    #pragma unroll
    for (int i = 0; i < 4; ++i)
      #pragma unroll
      for (int j = 0; j < 4; ++j)
        acc[i][j] = __builtin_amdgcn_mfma_f32_16x16x32_bf16(af[i], bfr[j], acc[i][j], 0, 0, 0);
    __syncthreads();
  }

  const int orow0 = blockIdx.y*128 + row0 + kq*4;
  const int ocol0 = blockIdx.x*128 + col0 + lr;
  #pragma unroll
  for (int i = 0; i < 4; ++i){
    #pragma unroll
    for (int j = 0; j < 4; ++j){
      #pragma unroll
      for (int r = 0; r < 4; ++r){
        float v = acc[i][j][r];
        if (ACT == 1)      v = v / (1.f + __expf(-v));   // silu
        else if (ACT == 2) v = 1.f / (1.f + __expf(-v)); // sigmoid
        size_t off = (size_t)(orow0 + i*16 + r)*Ncols + (ocol0 + j*16);
        if (OUTBF) ((uint16_t*)Cout)[off] = f2bf(v);
        else       ((float*)Cout)[off]    = v;
      }
    }
  }
}

// ---------------------------------------------- per-chunk state contribution
// MsumT[ic,b,h][e][d] = sum_j v[j,e] * dk[j] * k[j,d], dk[j]=exp(ld*(C-1-j))
__global__ __launch_bounds__(256)
void chunk_state_kernel(const uint16_t* __restrict__ kb, const uint16_t* __restrict__ vb,
                        const float* __restrict__ log_decay, uint16_t* __restrict__ MsumT)
{
  __shared__ __align__(16) uint16_t vT[128*128];
  __shared__ __align__(16) uint16_t kT[128*128];
  const int h = blockIdx.x, b = blockIdx.y, ic = blockIdx.z;
  const int t    = threadIdx.x;
  const int lane = t & 63, wave = t >> 6;
  const int wm = wave >> 1, wn = wave & 1;
  const int e0 = wm*64, d0 = wn*64;
  const int lr = lane & 15, kq = lane >> 4;
  const float ld = log_decay[h];
  const size_t rowbase = (size_t)b*N_ + (size_t)ic*C_;

  #pragma unroll 4
  for (int it = 0; it < 64; ++it){
    int idx = t + it*256;
    int j = idx >> 7, e = idx & 127;       // e doubles as d for kT
    uint16_t vv = vb[(rowbase + j)*D_ + h*HD_ + e];
    float kf = bf2f(kb[(rowbase + j)*D_ + h*HD_ + e]) * __expf(ld * (float)(C_ - 1 - j));
    vT[swz(e, j)] = vv;
    kT[swz(e, j)] = f2bf(kf);
  }
  __syncthreads();

  const f32x4 zero = {0.f, 0.f, 0.f, 0.f};
  f32x4 acc[4][4];
  #pragma unroll
  for (int i = 0; i < 4; ++i)
    #pragma unroll
    for (int j = 0; j < 4; ++j) acc[i][j] = zero;

  #pragma unroll
  for (int kt = 0; kt < 4; ++kt){
    bf16x8 af[4], bfr[4];
    #pragma unroll
    for (int i = 0; i < 4; ++i)
      af[i]  = *(const bf16x8*)(vT + swz(e0 + i*16 + lr, kt*32 + kq*8));
    #pragma unroll
    for (int j = 0; j < 4; ++j)
      bfr[j] = *(const bf16x8*)(kT + swz(d0 + j*16 + lr, kt*32 + kq*8));
    #pragma unroll
    for (int i = 0; i < 4; ++i)
      #pragma unroll
      for (int j = 0; j < 4; ++j)
        acc[i][j] = __builtin_amdgcn_mfma_f32_16x16x32_bf16(af[i], bfr[j], acc[i][j], 0, 0, 0);
  }

  uint16_t* Mout = MsumT + (((size_t)ic*B_ + b)*H_ + h)*(size_t)(HD_*HD_);
  #pragma unroll
  for (int i = 0; i < 4; ++i)
    #pragma unroll
    for (int j = 0; j < 4; ++j)
      #pragma unroll
      for (int r = 0; r < 4; ++r)
        Mout[(size_t)(e0 + i*16 + kq*4 + r)*HD_ + d0 + j*16 + lr] = f2bf(acc[i][j][r]);
}

// -------------------------------------------------- inter-chunk state scan
// StT[ic] = state BEFORE chunk ic (transposed layout [e][d], bf16)
__global__ __launch_bounds__(256)
void scan_kernel(const uint16_t* __restrict__ MsumT, const float* __restrict__ log_decay,
                 uint16_t* __restrict__ StT)
{
  const int h = blockIdx.x, b = blockIdx.y;
  const float ld = log_decay[h];
  const float dS = __expf(ld * (float)C_);
  float cur[64];
  #pragma unroll
  for (int r = 0; r < 64; ++r) cur[r] = 0.f;
  for (int i = 0; i < NC_; ++i){
    const size_t base = (((size_t)i*B_ + b)*H_ + h)*(size_t)(HD_*HD_);
    #pragma unroll
    for (int r = 0; r < 64; ++r){
      int idx = threadIdx.x + r*256;
      StT[base + idx] = f2bf(cur[r]);
      cur[r] = cur[r]*dS + bf2f(MsumT[base + idx]);
    }
  }
}

// ------------------------------------------------------ intra-chunk attention
// o = (q@k^T ∘ Dm) @ v + dq ⊙ (q @ S_start)
__global__ __launch_bounds__(256)
void attn_kernel(const uint16_t* __restrict__ qb, const uint16_t* __restrict__ kb,
                 const uint16_t* __restrict__ vb, const uint16_t* __restrict__ StT,
                 const float* __restrict__ log_decay, float* __restrict__ o_attn)
{
  __shared__ __align__(16) uint16_t Ps[128*128];
  __shared__ __align__(16) uint16_t vT[128*128];
  const int h = blockIdx.x, b = blockIdx.y, ic = blockIdx.z;
  const int t    = threadIdx.x;
  const int lane = t & 63, wave = t >> 6;
  const int wm = wave >> 1, wn = wave & 1;
  const int row0 = wm*64, col0 = wn*64;
  const int lr = lane & 15, kq = lane >> 4;
  const float ld = log_decay[h];
  const size_t rowbase = (size_t)b*N_ + (size_t)ic*C_;

  // stage v^T
  #pragma unroll 4
  for (int it = 0; it < 64; ++it){
    int idx = t + it*256;
    int j = idx >> 7, e = idx & 127;
    vT[swz(e, j)] = vb[(rowbase + j)*D_ + h*HD_ + e];
  }

  const f32x4 zero = {0.f, 0.f, 0.f, 0.f};
  f32x4 acc[4][4];
  #pragma unroll
  for (int i = 0; i < 4; ++i)
    #pragma unroll
    for (int j = 0; j < 4; ++j) acc[i][j] = zero;

  // phase A: P = (q @ k^T) ∘ Dm  (q,k frags straight from global, cache-hot)
  #pragma unroll
  for (int kt = 0; kt < 4; ++kt){
    bf16x8 af[4], bfr[4];
    #pragma unroll
    for (int i = 0; i < 4; ++i)
      af[i]  = *(const bf16x8*)(qb + (rowbase + row0 + i*16 + lr)*D_ + h*HD_ + kt*32 + kq*8);
    #pragma unroll
    for (int j = 0; j < 4; ++j)
      bfr[j] = *(const bf16x8*)(kb + (rowbase + col0 + j*16 + lr)*D_ + h*HD_ + kt*32 + kq*8);
    #pragma unroll
    for (int i = 0; i < 4; ++i)
      #pragma unroll
      for (int j = 0; j < 4; ++j)
        acc[i][j] = __builtin_amdgcn_mfma_f32_16x16x32_bf16(af[i], bfr[j], acc[i][j], 0, 0, 0);
  }
  #pragma unroll
  for (int i = 0; i < 4; ++i)
    #pragma unroll
    for (int j = 0; j < 4; ++j)
      #pragma unroll
      for (int r = 0; r < 4; ++r){
        int row = row0 + i*16 + kq*4 + r;
        int col = col0 + j*16 + lr;
        int dlt = row - col;
        float f = (dlt >= 0) ? __expf(ld * (float)dlt) : 0.f;
        Ps[swz(row, col)] = f2bf(acc[i][j][r] * f);
      }

  // phase B1: o2 = q @ S_start  (S stored transposed: StT[e][d])
  #pragma unroll
  for (int i = 0; i < 4; ++i)
    #pragma unroll
    for (int j = 0; j < 4; ++j) acc[i][j] = zero;
  const uint16_t* Sb = StT + (((size_t)ic*B_ + b)*H_ + h)*(size_t)(HD_*HD_);
  #pragma unroll
  for (int kt = 0; kt < 4; ++kt){
    bf16x8 af[4], bfr[4];
    #pragma unroll
    for (int i = 0; i < 4; ++i)
      af[i]  = *(const bf16x8*)(qb + (rowbase + row0 + i*16 + lr)*D_ + h*HD_ + kt*32 + kq*8);
    #pragma unroll
    for (int j = 0; j < 4; ++j)
      bfr[j] = *(const bf16x8*)(Sb + (size_t)(col0 + j*16 + lr)*HD_ + kt*32 + kq*8);
    #pragma unroll
    for (int i = 0; i < 4; ++i)
      #pragma unroll
      for (int j = 0; j < 4; ++j)
        acc[i][j] = __builtin_amdgcn_mfma_f32_16x16x32_bf16(af[i], bfr[j], acc[i][j], 0, 0, 0);
  }
  // scale o2 rows by dq[row] = exp(ld*(row+1))
  #pragma unroll
  for (int i = 0; i < 4; ++i)
    #pragma unroll
    for (int r = 0; r < 4; ++r){
      float dqv = __expf(ld * (float)(row0 + i*16 + kq*4 + r + 1));
      #pragma unroll
      for (int j = 0; j < 4; ++j) acc[i][j][r] *= dqv;
    }

  __syncthreads();   // Ps + vT visible to all waves

  // phase B2: o += P @ v  (both operands from swizzled LDS)
  #pragma unroll
  for (int kt = 0; kt < 4; ++kt){
    bf16x8 af[4], bfr[4];
    #pragma unroll
    for (int i = 0; i < 4; ++i)
      af[i]  = *(const bf16x8*)(Ps + swz(row0 + i*16 + lr, kt*32 + kq*8));
    #pragma unroll
    for (int j = 0; j < 4; ++j)
      bfr[j] = *(const bf16x8*)(vT + swz(col0 + j*16 + lr, kt*32 + kq*8));
    #pragma unroll
    for (int i = 0; i < 4; ++i)
      #pragma unroll
      for (int j = 0; j < 4; ++j)
        acc[i][j] = __builtin_amdgcn_mfma_f32_16x16x32_bf16(af[i], bfr[j], acc[i][j], 0, 0, 0);
  }

  #pragma unroll
  for (int i = 0; i < 4; ++i)
    #pragma unroll
    for (int j = 0; j < 4; ++j)
      #pragma unroll
      for (int r = 0; r < 4; ++r){
        int row = row0 + i*16 + kq*4 + r;
        int col = col0 + j*16 + lr;
        o_attn[(rowbase + row)*D_ + h*HD_ + col] = acc[i][j][r];
      }
}

// --------------------------------------------- gate ⊙ + rmsnorm + cast bf16
__global__ __launch_bounds__(256)
void gate_norm_kernel(const float* __restrict__ o_attn, const uint16_t* __restrict__ gateb,
                      const float* __restrict__ norm_w, uint16_t* __restrict__ on)
{
  const int row = blockIdx.x;
  const int t = threadIdx.x;
  const int c1 = t*4, c2 = 1024 + t*4;
  const float*    orow = o_attn + (size_t)row*D_;
  const uint16_t* grow = gateb  + (size_t)row*D_;
  float4  o1 = *(const float4*)(orow + c1);
  float4  o2 = *(const float4*)(orow + c2);
  ushort4 g1 = *(const ushort4*)(grow + c1);
  ushort4 g2 = *(const ushort4*)(grow + c2);
  float v[8];
  v[0] = o1.x*bf2f(g1.x); v[1] = o1.y*bf2f(g1.y); v[2] = o1.z*bf2f(g1.z); v[3] = o1.w*bf2f(g1.w);
  v[4] = o2.x*bf2f(g2.x); v[5] = o2.y*bf2f(g2.y); v[6] = o2.z*bf2f(g2.z); v[7] = o2.w*bf2f(g2.w);
  float s = 0.f;
  #pragma unroll
  for (int k = 0; k < 8; ++k) s += v[k]*v[k];
  #pragma unroll
  for (int off = 32; off > 0; off >>= 1) s += __shfl_down(s, off);
  __shared__ float red[4];
  if ((t & 63) == 0) red[t >> 6] = s;
  __syncthreads();
  float total = red[0] + red[1] + red[2] + red[3];
  float scale = rsqrtf(total * (1.f/(float)D_) + 1e-6f);
  float4 w1 = *(const float4*)(norm_w + c1);
  float4 w2 = *(const float4*)(norm_w + c2);
  ushort4 b1, b2;
  b1.x = f2bf(v[0]*scale*w1.x); b1.y = f2bf(v[1]*scale*w1.y);
  b1.z = f2bf(v[2]*scale*w1.z); b1.w = f2bf(v[3]*scale*w1.w);
  b2.x = f2bf(v[4]*scale*w2.x); b2.y = f2bf(v[5]*scale*w2.y);
  b2.z = f2bf(v[6]*scale*w2.z); b2.w = f2bf(v[7]*scale*w2.w);
  *(ushort4*)(on + (size_t)row*D_ + c1) = b1;
  *(ushort4*)(on + (size_t)row*D_ + c2) = b2;
}

// =============================================================== launch
extern "C" void kernel_launch(void* const* d_in, const int* in_sizes, int n_in,
                              void* d_out, int out_size, void* d_ws, size_t ws_size,
                              hipStream_t stream) {
  const float* x         = (const float*)d_in[0];
  const float* log_decay = (const float*)d_in[1];
  const float* Wq        = (const float*)d_in[2];
  const float* Wk        = (const float*)d_in[3];
  const float* Wv        = (const float*)d_in[4];
  const float* Wo        = (const float*)d_in[5];
  const float* Wg1       = (const float*)d_in[6];
  const float* Wg2       = (const float*)d_in[7];
  const float* norm_w    = (const float*)d_in[8];
  float* out = (float*)d_out;

  // workspace layout (~210 MB total)
  uint8_t* p = (uint8_t*)d_ws;
  uint16_t* xb    = (uint16_t*)p; p += (size_t)M_*D_*2;
  uint16_t* WqT   = (uint16_t*)p; p += (size_t)D_*D_*2;
  uint16_t* WkT   = (uint16_t*)p; p += (size_t)D_*D_*2;
  uint16_t* WvT   = (uint16_t*)p; p += (size_t)D_*D_*2;
  uint16_t* WoT   = (uint16_t*)p; p += (size_t)D_*D_*2;
  uint16_t* Wg1T  = (uint16_t*)p; p += (size_t)HD_*D_*2;   // [128][2048]
  uint16_t* Wg2T  = (uint16_t*)p; p += (size_t)D_*HD_*2;   // [2048][128]
  uint16_t* qb    = (uint16_t*)p; p += (size_t)M_*D_*2;
  uint16_t* kb    = (uint16_t*)p; p += (size_t)M_*D_*2;
  uint16_t* vb    = (uint16_t*)p; p += (size_t)M_*D_*2;
  uint16_t* g1b   = (uint16_t*)p; p += (size_t)M_*HD_*2;
  uint16_t* gateb = (uint16_t*)p; p += (size_t)M_*D_*2;
  uint16_t* MsumT = (uint16_t*)p; p += (size_t)NC_*B_*H_*HD_*HD_*2;
  uint16_t* StT   = (uint16_t*)p; p += (size_t)NC_*B_*H_*HD_*HD_*2;
  float*    o_att = (float*)p;    p += (size_t)M_*D_*4;
  uint16_t* on    = (uint16_t*)p; p += (size_t)M_*D_*2;

  // 1. casts / weight transposes
  cast_kernel<<<(M_*D_)/1024, 256, 0, stream>>>(x, xb);
  transpose_cast<<<dim3(D_/32, D_/32), 256, 0, stream>>>(Wq,  WqT,  D_,  D_);
  transpose_cast<<<dim3(D_/32, D_/32), 256, 0, stream>>>(Wk,  WkT,  D_,  D_);
  transpose_cast<<<dim3(D_/32, D_/32), 256, 0, stream>>>(Wv,  WvT,  D_,  D_);
  transpose_cast<<<dim3(D_/32, D_/32), 256, 0, stream>>>(Wo,  WoT,  D_,  D_);
  transpose_cast<<<dim3(HD_/32, D_/32), 256, 0, stream>>>(Wg1, Wg1T, D_,  HD_);
  transpose_cast<<<dim3(D_/32, HD_/32), 256, 0, stream>>>(Wg2, Wg2T, HD_, D_);

  // 2. projections
  gemm_bt<1,1><<<dim3(D_/128,  M_/128), 256, 0, stream>>>(xb,  WqT,  qb,    M_, D_,  D_);
  gemm_bt<1,1><<<dim3(D_/128,  M_/128), 256, 0, stream>>>(xb,  WkT,  kb,    M_, D_,  D_);
  gemm_bt<1,1><<<dim3(D_/128,  M_/128), 256, 0, stream>>>(xb,  WvT,  vb,    M_, D_,  D_);
  gemm_bt<0,1><<<dim3(HD_/128, M_/128), 256, 0, stream>>>(xb,  Wg1T, g1b,   M_, HD_, D_);
  gemm_bt<2,1><<<dim3(D_/128,  M_/128), 256, 0, stream>>>(g1b, Wg2T, gateb, M_, D_,  HD_);

  // 3. attention: chunk states -> scan -> intra-chunk
  chunk_state_kernel<<<dim3(H_, B_, NC_), 256, 0, stream>>>(kb, vb, log_decay, MsumT);
  scan_kernel<<<dim3(H_, B_), 256, 0, stream>>>(MsumT, log_decay, StT);
  attn_kernel<<<dim3(H_, B_, NC_), 256, 0, stream>>>(qb, kb, vb, StT, log_decay, o_att);

  // 4. gate + rmsnorm + final projection
  gate_norm_kernel<<<M_, 256, 0, stream>>>(o_att, gateb, norm_w, on);
  gemm_bt<0,0><<<dim3(D_/128, M_/128), 256, 0, stream>>>(on, WoT, out, M_, D_, D_);
}

// Round 2
// 467.398 us; speedup vs baseline: 1.1234x; 1.1234x over previous
//
#include <hip/hip_runtime.h>
#include <hip/hip_bf16.h>
#include <cstdint>
#include <cstddef>

#define B_   2
#define N_   2048
#define D_   2048
#define H_   16
#define HD_  128
#define C_   128
#define NC_  16
#define M_   4096   // B_*N_
#define QKVG_ 8192  // fused projection width: q|k|v|gate

typedef __attribute__((ext_vector_type(8))) short bf16x8;
typedef __attribute__((ext_vector_type(4))) float f32x4;

__device__ __forceinline__ uint16_t f2bf(float f){
  __hip_bfloat16 h = __float2bfloat16(f);
  return *reinterpret_cast<uint16_t*>(&h);
}
__device__ __forceinline__ float bf2f(uint16_t u){
  union { uint32_t i; float f; } v; v.i = ((uint32_t)u) << 16; return v.f;
}

// async global->LDS, 16B per lane. LDS dest must be wave-uniform base + lane*16.
__device__ __forceinline__ void async16(const uint16_t* g, uint16_t* l){
  __builtin_amdgcn_global_load_lds(
      (const __attribute__((address_space(1))) void*)g,
      (__attribute__((address_space(3))) void*)l, 16, 0, 0);
}

// XOR swizzle for [128][128] bf16 LDS tiles (attention kernels): frag-read
// b128s tile 8 bank-groups x 8 lanes -> conflict-free.
__device__ __forceinline__ int swz(int row, int c){
  return row*128 + ((((c >> 3) ^ row) & 15) << 3) + (c & 7);
}

// XOR swizzle for [128][32] bf16 GEMM staging tiles: without it, row stride
// 64B puts all frag b128 reads on 2 of 8 bank-groups (8-way conflict,
// 4.2M conflict cycles/dispatch measured R1). With it: conflict-free.
__device__ __forceinline__ int swz32(int row, int kc8){  // kc8 in [0,4)
  return row*32 + (((kc8 ^ row) & 3) << 3);
}

// ---------------------------------------------------------------- cast fp32->bf16
__global__ __launch_bounds__(256) void cast_kernel(
    const float* __restrict__ x, uint16_t* __restrict__ y)
{
  int i = (blockIdx.x*256 + threadIdx.x)*4;
  float4 f = *(const float4*)(x + i);
  ushort4 u;
  u.x = f2bf(f.x); u.y = f2bf(f.y); u.z = f2bf(f.z); u.w = f2bf(f.w);
  *(ushort4*)(y + i) = u;
}

// ------------------------------------------- transpose-cast W[R][Cc] -> Wt[Cc][R]
__global__ __launch_bounds__(256) void transpose_cast(
    const float* __restrict__ W, uint16_t* __restrict__ Wt, int R, int Cc)
{
  __shared__ uint16_t tile[32][33];
  const int tx = threadIdx.x & 31;
  const int ty = threadIdx.x >> 5;            // 0..7
  const int r0 = blockIdx.y*32, c0 = blockIdx.x*32;
  #pragma unroll
  for (int rr = 0; rr < 4; ++rr){
    int r = ty + rr*8;
    tile[r][tx] = f2bf(W[(size_t)(r0 + r)*Cc + c0 + tx]);
  }
  __syncthreads();
  #pragma unroll
  for (int rr = 0; rr < 4; ++rr){
    int r = ty + rr*8;
    Wt[(size_t)(c0 + r)*R + r0 + tx] = tile[tx][r];
  }
}

// ------------------------------------------------------- m97-style GEMM (B^T)
// C[M][Ncols] = act(A[M][K] @ Bt[Ncols][K]^T), swizzled staging.
// ACT: 0 none, 1 silu, 2 sigmoid, 3 mixed (silu if blockIdx.x<48 else sigmoid).
// OUTBF: 1 bf16 out, 0 fp32 out.
template<int ACT, int OUTBF>
__global__ __launch_bounds__(256)
void gemm_bt(const uint16_t* __restrict__ A, const uint16_t* __restrict__ Bt,
             void* __restrict__ Cout, int M, int Ncols, int K)
{
  __shared__ __align__(16) uint16_t As[128*32];
  __shared__ __align__(16) uint16_t Bs[128*32];
  const int t    = threadIdx.x;
  const int lane = t & 63, wave = t >> 6;
  const int wm = wave >> 1, wn = wave & 1;
  const int row0 = wm*64, col0 = wn*64;
  const int lr = lane & 15, kq = lane >> 4;

  const uint16_t* Ap = A  + (size_t)(blockIdx.y*128)*K;
  const uint16_t* Bp = Bt + (size_t)(blockIdx.x*128)*K;

  const f32x4 zero = {0.f, 0.f, 0.f, 0.f};
  f32x4 acc[4][4];
  #pragma unroll
  for (int i = 0; i < 4; ++i)
    #pragma unroll
    for (int j = 0; j < 4; ++j) acc[i][j] = zero;

  // staging: thread t fills LDS slot t*8 (= row (t>>2), xor-slot (t&3)).
  // fetch the k-chunk that belongs in that swizzled slot.
  const int r0c = t >> 2;
  const int kc0 = ((t & 3) ^ (r0c & 3)) * 8;

  for (int k0 = 0; k0 < K; k0 += 32){
    async16(Ap + (size_t)r0c*K      + k0 + kc0, As + t*8);
    async16(Ap + (size_t)(r0c+64)*K + k0 + kc0, As + (t+256)*8);
    async16(Bp + (size_t)r0c*K      + k0 + kc0, Bs + t*8);
    async16(Bp + (size_t)(r0c+64)*K + k0 + kc0, Bs + (t+256)*8);
    __syncthreads();
    bf16x8 af[4], bfr[4];
    #pragma unroll
    for (int i = 0; i < 4; ++i)
      af[i]  = *(const bf16x8*)(As + swz32(row0 + i*16 + lr, kq));
    #pragma unroll
    for (int j = 0; j < 4; ++j)
      bfr[j] = *(const bf16x8*)(Bs + swz32(col0 + j*16 + lr, kq));
    #pragma unroll
    for (int i = 0; i < 4; ++i)
      #pragma unroll
      for (int j = 0; j < 4; ++j)
        acc[i][j] = __builtin_amdgcn_mfma_f32_16x16x32_bf16(af[i], bfr[j], acc[i][j], 0, 0, 0);
    __syncthreads();
  }

  const int mode = (ACT == 3) ? ((blockIdx.x < 48) ? 1 : 2) : ACT;
  const int orow0 = blockIdx.y*128 + row0 + kq*4;
  const int ocol0 = blockIdx.x*128 + col0 + lr;
  #pragma unroll
  for (int i = 0; i < 4; ++i){
    #pragma unroll
    for (int j = 0; j < 4; ++j){
      #pragma unroll
      for (int r = 0; r < 4; ++r){
        float v = acc[i][j][r];
        if (mode == 1)      v = v / (1.f + __expf(-v));   // silu
        else if (mode == 2) v = 1.f / (1.f + __expf(-v)); // sigmoid
        size_t off = (size_t)(orow0 + i*16 + r)*Ncols + (ocol0 + j*16);
        if (OUTBF) ((uint16_t*)Cout)[off] = f2bf(v);
        else       ((float*)Cout)[off]    = v;
      }
    }
  }
}

// ---------------------------------------------- per-chunk state contribution
// MsumT[ic,b,h][e][d] = sum_j v[j,e] * dk[j] * k[j,d], dk[j]=exp(ld*(C-1-j))
// kv rows live in the fused qkvg buffer with row stride QKVG_.
__global__ __launch_bounds__(256)
void chunk_state_kernel(const uint16_t* __restrict__ qkvg,
                        const float* __restrict__ log_decay, uint16_t* __restrict__ MsumT)
{
  __shared__ __align__(16) uint16_t vT[128*128];
  __shared__ __align__(16) uint16_t kT[128*128];
  const int h = blockIdx.x, b = blockIdx.y, ic = blockIdx.z;
  const int t    = threadIdx.x;
  const int lane = t & 63, wave = t >> 6;
  const int wm = wave >> 1, wn = wave & 1;
  const int e0 = wm*64, d0 = wn*64;
  const int lr = lane & 15, kq = lane >> 4;
  const float ld = log_decay[h];
  const size_t rowbase = (size_t)b*N_ + (size_t)ic*C_;
  const uint16_t* kb = qkvg + (size_t)D_;      // k slice
  const uint16_t* vb = qkvg + (size_t)2*D_;    // v slice

  #pragma unroll 4
  for (int it = 0; it < 64; ++it){
    int idx = t + it*256;
    int j = idx >> 7, e = idx & 127;
    uint16_t vv = vb[(rowbase + j)*QKVG_ + h*HD_ + e];
    float kf = bf2f(kb[(rowbase + j)*QKVG_ + h*HD_ + e]) * __expf(ld * (float)(C_ - 1 - j));
    vT[swz(e, j)] = vv;
    kT[swz(e, j)] = f2bf(kf);
  }
  __syncthreads();

  const f32x4 zero = {0.f, 0.f, 0.f, 0.f};
  f32x4 acc[4][4];
  #pragma unroll
  for (int i = 0; i < 4; ++i)
    #pragma unroll
    for (int j = 0; j < 4; ++j) acc[i][j] = zero;

  #pragma unroll
  for (int kt = 0; kt < 4; ++kt){
    bf16x8 af[4], bfr[4];
    #pragma unroll
    for (int i = 0; i < 4; ++i)
      af[i]  = *(const bf16x8*)(vT + swz(e0 + i*16 + lr, kt*32 + kq*8));
    #pragma unroll
    for (int j = 0; j < 4; ++j)
      bfr[j] = *(const bf16x8*)(kT + swz(d0 + j*16 + lr, kt*32 + kq*8));
    #pragma unroll
    for (int i = 0; i < 4; ++i)
      #pragma unroll
      for (int j = 0; j < 4; ++j)
        acc[i][j] = __builtin_amdgcn_mfma_f32_16x16x32_bf16(af[i], bfr[j], acc[i][j], 0, 0, 0);
  }

  uint16_t* Mout = MsumT + (((size_t)ic*B_ + b)*H_ + h)*(size_t)(HD_*HD_);
  #pragma unroll
  for (int i = 0; i < 4; ++i)
    #pragma unroll
    for (int j = 0; j < 4; ++j)
      #pragma unroll
      for (int r = 0; r < 4; ++r)
        Mout[(size_t)(e0 + i*16 + kq*4 + r)*HD_ + d0 + j*16 + lr] = f2bf(acc[i][j][r]);
}

// -------------------------------------------------- inter-chunk state scan
// StT[ic] = state BEFORE chunk ic. 256 blocks (z-split of the 16384 elems).
__global__ __launch_bounds__(256)
void scan_kernel(const uint16_t* __restrict__ MsumT, const float* __restrict__ log_decay,
                 uint16_t* __restrict__ StT)
{
  const int h = blockIdx.x, b = blockIdx.y;
  const float ld = log_decay[h];
  const float dS = __expf(ld * (float)C_);
  const int base_e = blockIdx.z*2048;
  float cur[8];
  #pragma unroll
  for (int r = 0; r < 8; ++r) cur[r] = 0.f;
  for (int i = 0; i < NC_; ++i){
    const size_t base = (((size_t)i*B_ + b)*H_ + h)*(size_t)(HD_*HD_) + base_e;
    #pragma unroll
    for (int r = 0; r < 8; ++r){
      int idx = threadIdx.x + r*256;
      StT[base + idx] = f2bf(cur[r]);
      cur[r] = cur[r]*dS + bf2f(MsumT[base + idx]);
    }
  }
}

// ------------------------------------------------------ intra-chunk attention
// o = (q@k^T ∘ Dm) @ v + dq ⊙ (q @ S_start)
__global__ __launch_bounds__(256)
void attn_kernel(const uint16_t* __restrict__ qkvg, const uint16_t* __restrict__ StT,
                 const float* __restrict__ log_decay, float* __restrict__ o_attn)
{
  __shared__ __align__(16) uint16_t Ps[128*128];
  __shared__ __align__(16) uint16_t vT[128*128];
  const int h = blockIdx.x, b = blockIdx.y, ic = blockIdx.z;
  const int t    = threadIdx.x;
  const int lane = t & 63, wave = t >> 6;
  const int wm = wave >> 1, wn = wave & 1;
  const int row0 = wm*64, col0 = wn*64;
  const int lr = lane & 15, kq = lane >> 4;
  const float ld = log_decay[h];
  const size_t rowbase = (size_t)b*N_ + (size_t)ic*C_;
  const uint16_t* qb = qkvg;
  const uint16_t* kb = qkvg + (size_t)D_;
  const uint16_t* vb = qkvg + (size_t)2*D_;

  // stage v^T
  #pragma unroll 4
  for (int it = 0; it < 64; ++it){
    int idx = t + it*256;
    int j = idx >> 7, e = idx & 127;
    vT[swz(e, j)] = vb[(rowbase + j)*QKVG_ + h*HD_ + e];
  }

  const f32x4 zero = {0.f, 0.f, 0.f, 0.f};
  f32x4 acc[4][4];
  #pragma unroll
  for (int i = 0; i < 4; ++i)
    #pragma unroll
    for (int j = 0; j < 4; ++j) acc[i][j] = zero;

  // phase A: P = (q @ k^T) ∘ Dm
  #pragma unroll
  for (int kt = 0; kt < 4; ++kt){
    bf16x8 af[4], bfr[4];
    #pragma unroll
    for (int i = 0; i < 4; ++i)
      af[i]  = *(const bf16x8*)(qb + (rowbase + row0 + i*16 + lr)*QKVG_ + h*HD_ + kt*32 + kq*8);
    #pragma unroll
    for (int j = 0; j < 4; ++j)
      bfr[j] = *(const bf16x8*)(kb + (rowbase + col0 + j*16 + lr)*QKVG_ + h*HD_ + kt*32 + kq*8);
    #pragma unroll
    for (int i = 0; i < 4; ++i)
      #pragma unroll
      for (int j = 0; j < 4; ++j)
        acc[i][j] = __builtin_amdgcn_mfma_f32_16x16x32_bf16(af[i], bfr[j], acc[i][j], 0, 0, 0);
  }
  #pragma unroll
  for (int i = 0; i < 4; ++i)
    #pragma unroll
    for (int j = 0; j < 4; ++j)
      #pragma unroll
      for (int r = 0; r < 4; ++r){
        int row = row0 + i*16 + kq*4 + r;
        int col = col0 + j*16 + lr;
        int dlt = row - col;
        float f = (dlt >= 0) ? __expf(ld * (float)dlt) : 0.f;
        Ps[swz(row, col)] = f2bf(acc[i][j][r] * f);
      }

  // phase B1: o2 = q @ S_start  (StT[e][d]: frag row=e(out col), k=d)
  #pragma unroll
  for (int i = 0; i < 4; ++i)
    #pragma unroll
    for (int j = 0; j < 4; ++j) acc[i][j] = zero;
  const uint16_t* Sb = StT + (((size_t)ic*B_ + b)*H_ + h)*(size_t)(HD_*HD_);
  #pragma unroll
  for (int kt = 0; kt < 4; ++kt){
    bf16x8 af[4], bfr[4];
    #pragma unroll
    for (int i = 0; i < 4; ++i)
      af[i]  = *(const bf16x8*)(qb + (rowbase + row0 + i*16 + lr)*QKVG_ + h*HD_ + kt*32 + kq*8);
    #pragma unroll
    for (int j = 0; j < 4; ++j)
      bfr[j] = *(const bf16x8*)(Sb + (size_t)(col0 + j*16 + lr)*HD_ + kt*32 + kq*8);
    #pragma unroll
    for (int i = 0; i < 4; ++i)
      #pragma unroll
      for (int j = 0; j < 4; ++j)
        acc[i][j] = __builtin_amdgcn_mfma_f32_16x16x32_bf16(af[i], bfr[j], acc[i][j], 0, 0, 0);
  }
  // scale o2 rows by dq[row] = exp(ld*(row+1))
  #pragma unroll
  for (int i = 0; i < 4; ++i)
    #pragma unroll
    for (int r = 0; r < 4; ++r){
      float dqv = __expf(ld * (float)(row0 + i*16 + kq*4 + r + 1));
      #pragma unroll
      for (int j = 0; j < 4; ++j) acc[i][j][r] *= dqv;
    }

  __syncthreads();   // Ps + vT visible to all waves

  // phase B2: o += P @ v
  #pragma unroll
  for (int kt = 0; kt < 4; ++kt){
    bf16x8 af[4], bfr[4];
    #pragma unroll
    for (int i = 0; i < 4; ++i)
      af[i]  = *(const bf16x8*)(Ps + swz(row0 + i*16 + lr, kt*32 + kq*8));
    #pragma unroll
    for (int j = 0; j < 4; ++j)
      bfr[j] = *(const bf16x8*)(vT + swz(col0 + j*16 + lr, kt*32 + kq*8));
    #pragma unroll
    for (int i = 0; i < 4; ++i)
      #pragma unroll
      for (int j = 0; j < 4; ++j)
        acc[i][j] = __builtin_amdgcn_mfma_f32_16x16x32_bf16(af[i], bfr[j], acc[i][j], 0, 0, 0);
  }

  #pragma unroll
  for (int i = 0; i < 4; ++i)
    #pragma unroll
    for (int j = 0; j < 4; ++j)
      #pragma unroll
      for (int r = 0; r < 4; ++r){
        int row = row0 + i*16 + kq*4 + r;
        int col = col0 + j*16 + lr;
        o_attn[(rowbase + row)*D_ + h*HD_ + col] = acc[i][j][r];
      }
}

// --------------------------------------------- gate ⊙ + rmsnorm + cast bf16
__global__ __launch_bounds__(256)
void gate_norm_kernel(const float* __restrict__ o_attn, const uint16_t* __restrict__ qkvg,
                      const float* __restrict__ norm_w, uint16_t* __restrict__ on)
{
  const int row = blockIdx.x;
  const int t = threadIdx.x;
  const int c1 = t*4, c2 = 1024 + t*4;
  const float*    orow = o_attn + (size_t)row*D_;
  const uint16_t* grow = qkvg + (size_t)row*QKVG_ + 3*D_;  // gate slice
  float4  o1 = *(const float4*)(orow + c1);
  float4  o2 = *(const float4*)(orow + c2);
  ushort4 g1 = *(const ushort4*)(grow + c1);
  ushort4 g2 = *(const ushort4*)(grow + c2);
  float v[8];
  v[0] = o1.x*bf2f(g1.x); v[1] = o1.y*bf2f(g1.y); v[2] = o1.z*bf2f(g1.z); v[3] = o1.w*bf2f(g1.w);
  v[4] = o2.x*bf2f(g2.x); v[5] = o2.y*bf2f(g2.y); v[6] = o2.z*bf2f(g2.z); v[7] = o2.w*bf2f(g2.w);
  float s = 0.f;
  #pragma unroll
  for (int k = 0; k < 8; ++k) s += v[k]*v[k];
  #pragma unroll
  for (int off = 32; off > 0; off >>= 1) s += __shfl_down(s, off);
  __shared__ float red[4];
  if ((t & 63) == 0) red[t >> 6] = s;
  __syncthreads();
  float total = red[0] + red[1] + red[2] + red[3];
  float scale = rsqrtf(total * (1.f/(float)D_) + 1e-6f);
  float4 w1 = *(const float4*)(norm_w + c1);
  float4 w2 = *(const float4*)(norm_w + c2);
  ushort4 b1, b2;
  b1.x = f2bf(v[0]*scale*w1.x); b1.y = f2bf(v[1]*scale*w1.y);
  b1.z = f2bf(v[2]*scale*w1.z); b1.w = f2bf(v[3]*scale*w1.w);
  b2.x = f2bf(v[4]*scale*w2.x); b2.y = f2bf(v[5]*scale*w2.y);
  b2.z = f2bf(v[6]*scale*w2.z); b2.w = f2bf(v[7]*scale*w2.w);
  *(ushort4*)(on + (size_t)row*D_ + c1) = b1;
  *(ushort4*)(on + (size_t)row*D_ + c2) = b2;
}

// =============================================================== launch
extern "C" void kernel_launch(void* const* d_in, const int* in_sizes, int n_in,
                              void* d_out, int out_size, void* d_ws, size_t ws_size,
                              hipStream_t stream) {
  const float* x         = (const float*)d_in[0];
  const float* log_decay = (const float*)d_in[1];
  const float* Wq        = (const float*)d_in[2];
  const float* Wk        = (const float*)d_in[3];
  const float* Wv        = (const float*)d_in[4];
  const float* Wo        = (const float*)d_in[5];
  const float* Wg1       = (const float*)d_in[6];
  const float* Wg2       = (const float*)d_in[7];
  const float* norm_w    = (const float*)d_in[8];
  float* out = (float*)d_out;

  // workspace layout (~160 MB with aliasing)
  uint8_t* p = (uint8_t*)d_ws;
  uint16_t* xb    = (uint16_t*)p; p += (size_t)M_*D_*2;        // later reused as `on`
  uint16_t* WT    = (uint16_t*)p; p += (size_t)QKVG_*D_*2;     // later reused as o_att
  uint16_t* WoT   = (uint16_t*)p; p += (size_t)D_*D_*2;
  uint16_t* Wg1b  = (uint16_t*)p; p += (size_t)D_*HD_*2;       // Wg1 cast, [2048][128]
  uint16_t* Wg2T  = (uint16_t*)p; p += (size_t)D_*HD_*2;       // Wg2^T,    [2048][128]
  uint16_t* qkvg  = (uint16_t*)p; p += (size_t)M_*QKVG_*2;
  uint16_t* MsumT = (uint16_t*)p; p += (size_t)NC_*B_*H_*HD_*HD_*2;
  uint16_t* StT   = (uint16_t*)p; p += (size_t)NC_*B_*H_*HD_*HD_*2;
  float*    o_att = (float*)WT;        // alias: WT dead after fused GEMM
  uint16_t* on    = xb;                // alias: xb dead after fused GEMM

  // 1. casts / weight transposes. WT rows: [0,2048)=Wq^T [2048,4096)=Wk^T
  //    [4096,6144)=Wv^T [6144,8192)=Wg^T(computed below)
  cast_kernel<<<(M_*D_)/1024, 256, 0, stream>>>(x, xb);
  cast_kernel<<<(D_*HD_)/1024, 256, 0, stream>>>(Wg1, Wg1b);
  transpose_cast<<<dim3(D_/32, D_/32), 256, 0, stream>>>(Wq, WT,               D_, D_);
  transpose_cast<<<dim3(D_/32, D_/32), 256, 0, stream>>>(Wk, WT + 2048*2048,   D_, D_);
  transpose_cast<<<dim3(D_/32, D_/32), 256, 0, stream>>>(Wv, WT + 2*2048*2048, D_, D_);
  transpose_cast<<<dim3(D_/32, D_/32), 256, 0, stream>>>(Wo, WoT,              D_, D_);
  transpose_cast<<<dim3(D_/32, HD_/32), 256, 0, stream>>>(Wg2, Wg2T, HD_, D_);

  // 2. Wg^T = (Wg1 @ Wg2)^T: C[c][k] = sum_j Wg2T[c][j]*Wg1b[k][j]
  gemm_bt<0,1><<<dim3(D_/128, D_/128), 256, 0, stream>>>(Wg2T, Wg1b, WT + (size_t)3*2048*2048, D_, D_, HD_);

  // 3. fused projection: [q|k|v|gate] = act(x @ [Wq|Wk|Wv|Wg])
  gemm_bt<3,1><<<dim3(QKVG_/128, M_/128), 256, 0, stream>>>(xb, WT, qkvg, M_, QKVG_, D_);

  // 4. attention: chunk states -> scan -> intra-chunk
  chunk_state_kernel<<<dim3(H_, B_, NC_), 256, 0, stream>>>(qkvg, log_decay, MsumT);
  scan_kernel<<<dim3(H_, B_, 8), 256, 0, stream>>>(MsumT, log_decay, StT);
  attn_kernel<<<dim3(H_, B_, NC_), 256, 0, stream>>>(qkvg, StT, log_decay, o_att);

  // 5. gate + rmsnorm + final projection
  gate_norm_kernel<<<M_, 256, 0, stream>>>(o_att, qkvg, norm_w, on);
  gemm_bt<0,0><<<dim3(D_/128, M_/128), 256, 0, stream>>>(on, WoT, out, M_, D_, D_);
}

// Round 3
// 449.876 us; speedup vs baseline: 1.1671x; 1.0389x over previous
//
#include <hip/hip_runtime.h>
#include <hip/hip_bf16.h>
#include <cstdint>
#include <cstddef>

#define B_   2
#define N_   2048
#define D_   2048
#define H_   16
#define HD_  128
#define C_   128
#define NC_  16
#define M_   4096   // B_*N_
#define QKVG_ 8192  // fused projection width: q|k|v|gate

typedef __attribute__((ext_vector_type(8))) short bf16x8;
typedef __attribute__((ext_vector_type(4))) float f32x4;
typedef __attribute__((ext_vector_type(16))) float f32x16;

__device__ __forceinline__ uint16_t f2bf(float f){
  __hip_bfloat16 h = __float2bfloat16(f);
  return *reinterpret_cast<uint16_t*>(&h);
}
__device__ __forceinline__ float bf2f(uint16_t u){
  union { uint32_t i; float f; } v; v.i = ((uint32_t)u) << 16; return v.f;
}

// async global->LDS, 16B per lane. LDS dest must be wave-uniform base + lane*16.
__device__ __forceinline__ void async16(const uint16_t* g, uint16_t* l){
  __builtin_amdgcn_global_load_lds(
      (const __attribute__((address_space(1))) void*)g,
      (__attribute__((address_space(3))) void*)l, 16, 0, 0);
}

// [128][128] attention-tile swizzle (unchanged, verified-correct kernels use it)
__device__ __forceinline__ int swz(int row, int c){
  return row*128 + ((((c >> 3) ^ row) & 15) << 3) + (c & 7);
}

// ---------------------------------------------------------------- cast fp32->bf16
__global__ __launch_bounds__(256) void cast_kernel(
    const float* __restrict__ x, uint16_t* __restrict__ y)
{
  int i = (blockIdx.x*256 + threadIdx.x)*4;
  float4 f = *(const float4*)(x + i);
  ushort4 u;
  u.x = f2bf(f.x); u.y = f2bf(f.y); u.z = f2bf(f.z); u.w = f2bf(f.w);
  *(ushort4*)(y + i) = u;
}

// ---------------------------------------- all weight prep in ONE launch (grid.z)
// z=0..2: Wq/Wk/Wv -> WT slices (2048x2048 transpose-cast)
// z=3   : Wo -> WoT
// z=4   : Wg2 [128][2048] -> Wg2T [2048][128]   (by<4)
// z=5   : Wg1 [2048][128] straight cast          (bx<4)
__global__ __launch_bounds__(256)
void prep_weights(const float* __restrict__ Wq, const float* __restrict__ Wk,
                  const float* __restrict__ Wv, const float* __restrict__ Wo,
                  const float* __restrict__ Wg2, const float* __restrict__ Wg1,
                  uint16_t* __restrict__ WT, uint16_t* __restrict__ WoT,
                  uint16_t* __restrict__ Wg2T, uint16_t* __restrict__ Wg1b)
{
  const int z = blockIdx.z;
  const int tx = threadIdx.x & 31;
  const int ty = threadIdx.x >> 5;   // 0..7
  __shared__ uint16_t tile[32][33];

  if (z == 5){                       // straight cast Wg1
    if (blockIdx.x >= 4) return;
    const int r0 = blockIdx.y*32, c0 = blockIdx.x*32;
    #pragma unroll
    for (int rr = 0; rr < 4; ++rr){
      int r = r0 + ty + rr*8;
      Wg1b[(size_t)r*HD_ + c0 + tx] = f2bf(Wg1[(size_t)r*HD_ + c0 + tx]);
    }
    return;
  }

  const float* src; uint16_t* dst; int R, Cc;
  if (z < 3)      { src = (z==0)?Wq:(z==1)?Wk:Wv; dst = WT + (size_t)z*D_*D_; R = D_; Cc = D_; }
  else if (z == 3){ src = Wo;  dst = WoT;  R = D_;  Cc = D_; }
  else            { if (blockIdx.y >= 4) return;
                    src = Wg2; dst = Wg2T; R = HD_; Cc = D_; }

  const int r0 = blockIdx.y*32, c0 = blockIdx.x*32;
  #pragma unroll
  for (int rr = 0; rr < 4; ++rr){
    int r = ty + rr*8;
    tile[r][tx] = f2bf(src[(size_t)(r0 + r)*Cc + c0 + tx]);
  }
  __syncthreads();
  #pragma unroll
  for (int rr = 0; rr < 4; ++rr){
    int r = ty + rr*8;
    dst[(size_t)(c0 + r)*R + r0 + tx] = tile[tx][r];
  }
}

// ------------------------------------------------- GEMM v2: BK=64, 32x32x16 MFMA
// C[M][Ncols] = act(A[M][K] @ Bt[Ncols][K]^T). 128x128 block, 4 waves, 2x2
// 32x32 tiles per wave. k-chunks (8 elem = 16B) XOR-swizzled by row&7 to break
// the 128B-row-stride bank alias. blockIdx.z = split-K slice of length klen;
// for OUTBF=0, slice z writes to Cout + z*M*Ncols (fp32 partials).
// ACT: 0 none, 1 silu, 2 sigmoid, 3 mixed (silu if blockIdx.x<48 else sigmoid).
template<int ACT, int OUTBF>
__global__ __launch_bounds__(256)
void gemm_bt2(const uint16_t* __restrict__ A, const uint16_t* __restrict__ Bt,
              void* __restrict__ Cout, int M, int Ncols, int K, int klen)
{
  __shared__ __align__(16) uint16_t As[128*64];
  __shared__ __align__(16) uint16_t Bs[128*64];
  const int t    = threadIdx.x;
  const int lane = t & 63, wave = t >> 6;
  const int wm = wave >> 1, wn = wave & 1;
  const int row0 = wm*64, col0 = wn*64;
  const int lm = lane & 31, lh = lane >> 5;

  const uint16_t* Ap = A  + (size_t)(blockIdx.y*128)*K;
  const uint16_t* Bp = Bt + (size_t)(blockIdx.x*128)*K;
  const int kbeg = blockIdx.z * klen;

  f32x16 acc[2][2];
  #pragma unroll
  for (int i = 0; i < 2; ++i)
    #pragma unroll
    for (int j = 0; j < 2; ++j)
      #pragma unroll
      for (int r = 0; r < 16; ++r) acc[i][j][r] = 0.f;

  // staging map for call c (c=0..3): thread t fills LDS slot c*2048 + t*8
  // (row = c*32 + (t>>3), lds-chunk = t&7); fetch global chunk (t&7)^((t>>3)&7).
  const int srow = t >> 3;                       // 0..31 (+ c*32)
  const int gch  = (t & 7) ^ (srow & 7);         // xor-swizzled k-chunk
  const size_t aoff0 = (size_t)srow*K + gch*8;

  for (int k0 = kbeg; k0 < kbeg + klen; k0 += 64){
    #pragma unroll
    for (int c = 0; c < 4; ++c){
      async16(Ap + (size_t)(c*32)*K + aoff0 + k0, As + c*2048 + t*8);
      async16(Bp + (size_t)(c*32)*K + aoff0 + k0, Bs + c*2048 + t*8);
    }
    __syncthreads();
    #pragma unroll
    for (int kh = 0; kh < 4; ++kh){
      bf16x8 af[2], bfr[2];
      const int ch = kh*2 + lh;                  // global k-chunk within tile
      #pragma unroll
      for (int i = 0; i < 2; ++i){
        int r = row0 + i*32 + lm;
        af[i] = *(const bf16x8*)(As + r*64 + ((ch ^ (r & 7)) << 3));
      }
      #pragma unroll
      for (int j = 0; j < 2; ++j){
        int r = col0 + j*32 + lm;
        bfr[j] = *(const bf16x8*)(Bs + r*64 + ((ch ^ (r & 7)) << 3));
      }
      #pragma unroll
      for (int i = 0; i < 2; ++i)
        #pragma unroll
        for (int j = 0; j < 2; ++j)
          acc[i][j] = __builtin_amdgcn_mfma_f32_32x32x16_bf16(af[i], bfr[j], acc[i][j], 0, 0, 0);
    }
    __syncthreads();
  }

  // epilogue. 32x32 C/D layout: col = lane&31, row = (r&3) + 8*(r>>2) + 4*lh
  const int mode = (ACT == 3) ? ((blockIdx.x < 48) ? 1 : 2) : ACT;
  uint16_t* outb = (uint16_t*)Cout;
  float*    outf = (float*)Cout + (OUTBF ? 0 : (size_t)blockIdx.z*M*Ncols);
  #pragma unroll
  for (int i = 0; i < 2; ++i){
    #pragma unroll
    for (int j = 0; j < 2; ++j){
      #pragma unroll
      for (int r = 0; r < 16; ++r){
        int row = blockIdx.y*128 + row0 + i*32 + (r & 3) + 8*(r >> 2) + 4*lh;
        int col = blockIdx.x*128 + col0 + j*32 + lm;
        float v = acc[i][j][r];
        if (mode == 1)      v = v / (1.f + __expf(-v));
        else if (mode == 2) v = 1.f / (1.f + __expf(-v));
        size_t off = (size_t)row*Ncols + col;
        if (OUTBF) outb[off] = f2bf(v);
        else       outf[off] = v;
      }
    }
  }
}

// ------------------------------------------------------ split-K partial add
__global__ __launch_bounds__(256)
void add_kernel(const float* __restrict__ p0, const float* __restrict__ p1,
                float* __restrict__ out)
{
  int i = (blockIdx.x*256 + threadIdx.x)*4;
  float4 a = *(const float4*)(p0 + i);
  float4 b = *(const float4*)(p1 + i);
  float4 o; o.x = a.x+b.x; o.y = a.y+b.y; o.z = a.z+b.z; o.w = a.w+b.w;
  *(float4*)(out + i) = o;
}

// ---------------------------------------------- per-chunk state contribution
// MsumT[ic,b,h][e][d] = sum_j v[j,e] * dk[j] * k[j,d], dk[j]=exp(ld*(C-1-j))
__global__ __launch_bounds__(256)
void chunk_state_kernel(const uint16_t* __restrict__ qkvg,
                        const float* __restrict__ log_decay, uint16_t* __restrict__ MsumT)
{
  __shared__ __align__(16) uint16_t vT[128*128];
  __shared__ __align__(16) uint16_t kT[128*128];
  const int h = blockIdx.x, b = blockIdx.y, ic = blockIdx.z;
  const int t    = threadIdx.x;
  const int lane = t & 63, wave = t >> 6;
  const int wm = wave >> 1, wn = wave & 1;
  const int e0 = wm*64, d0 = wn*64;
  const int lr = lane & 15, kq = lane >> 4;
  const float ld = log_decay[h];
  const size_t rowbase = (size_t)b*N_ + (size_t)ic*C_;
  const uint16_t* kb = qkvg + (size_t)D_;
  const uint16_t* vb = qkvg + (size_t)2*D_;

  #pragma unroll 4
  for (int it = 0; it < 64; ++it){
    int idx = t + it*256;
    int j = idx >> 7, e = idx & 127;
    uint16_t vv = vb[(rowbase + j)*QKVG_ + h*HD_ + e];
    float kf = bf2f(kb[(rowbase + j)*QKVG_ + h*HD_ + e]) * __expf(ld * (float)(C_ - 1 - j));
    vT[swz(e, j)] = vv;
    kT[swz(e, j)] = f2bf(kf);
  }
  __syncthreads();

  const f32x4 zero = {0.f, 0.f, 0.f, 0.f};
  f32x4 acc[4][4];
  #pragma unroll
  for (int i = 0; i < 4; ++i)
    #pragma unroll
    for (int j = 0; j < 4; ++j) acc[i][j] = zero;

  #pragma unroll
  for (int kt = 0; kt < 4; ++kt){
    bf16x8 af[4], bfr[4];
    #pragma unroll
    for (int i = 0; i < 4; ++i)
      af[i]  = *(const bf16x8*)(vT + swz(e0 + i*16 + lr, kt*32 + kq*8));
    #pragma unroll
    for (int j = 0; j < 4; ++j)
      bfr[j] = *(const bf16x8*)(kT + swz(d0 + j*16 + lr, kt*32 + kq*8));
    #pragma unroll
    for (int i = 0; i < 4; ++i)
      #pragma unroll
      for (int j = 0; j < 4; ++j)
        acc[i][j] = __builtin_amdgcn_mfma_f32_16x16x32_bf16(af[i], bfr[j], acc[i][j], 0, 0, 0);
  }

  uint16_t* Mout = MsumT + (((size_t)ic*B_ + b)*H_ + h)*(size_t)(HD_*HD_);
  #pragma unroll
  for (int i = 0; i < 4; ++i)
    #pragma unroll
    for (int j = 0; j < 4; ++j)
      #pragma unroll
      for (int r = 0; r < 4; ++r)
        Mout[(size_t)(e0 + i*16 + kq*4 + r)*HD_ + d0 + j*16 + lr] = f2bf(acc[i][j][r]);
}

// -------------------------------------------------- inter-chunk state scan
__global__ __launch_bounds__(256)
void scan_kernel(const uint16_t* __restrict__ MsumT, const float* __restrict__ log_decay,
                 uint16_t* __restrict__ StT)
{
  const int h = blockIdx.x, b = blockIdx.y;
  const float ld = log_decay[h];
  const float dS = __expf(ld * (float)C_);
  const int base_e = blockIdx.z*2048;
  float cur[8];
  #pragma unroll
  for (int r = 0; r < 8; ++r) cur[r] = 0.f;
  for (int i = 0; i < NC_; ++i){
    const size_t base = (((size_t)i*B_ + b)*H_ + h)*(size_t)(HD_*HD_) + base_e;
    #pragma unroll
    for (int r = 0; r < 8; ++r){
      int idx = threadIdx.x + r*256;
      StT[base + idx] = f2bf(cur[r]);
      cur[r] = cur[r]*dS + bf2f(MsumT[base + idx]);
    }
  }
}

// ------------------------------------------------------ intra-chunk attention
__global__ __launch_bounds__(256)
void attn_kernel(const uint16_t* __restrict__ qkvg, const uint16_t* __restrict__ StT,
                 const float* __restrict__ log_decay, float* __restrict__ o_attn)
{
  __shared__ __align__(16) uint16_t Ps[128*128];
  __shared__ __align__(16) uint16_t vT[128*128];
  const int h = blockIdx.x, b = blockIdx.y, ic = blockIdx.z;
  const int t    = threadIdx.x;
  const int lane = t & 63, wave = t >> 6;
  const int wm = wave >> 1, wn = wave & 1;
  const int row0 = wm*64, col0 = wn*64;
  const int lr = lane & 15, kq = lane >> 4;
  const float ld = log_decay[h];
  const size_t rowbase = (size_t)b*N_ + (size_t)ic*C_;
  const uint16_t* qb = qkvg;
  const uint16_t* kb = qkvg + (size_t)D_;
  const uint16_t* vb = qkvg + (size_t)2*D_;

  #pragma unroll 4
  for (int it = 0; it < 64; ++it){
    int idx = t + it*256;
    int j = idx >> 7, e = idx & 127;
    vT[swz(e, j)] = vb[(rowbase + j)*QKVG_ + h*HD_ + e];
  }

  const f32x4 zero = {0.f, 0.f, 0.f, 0.f};
  f32x4 acc[4][4];
  #pragma unroll
  for (int i = 0; i < 4; ++i)
    #pragma unroll
    for (int j = 0; j < 4; ++j) acc[i][j] = zero;

  // phase A: P = (q @ k^T) ∘ Dm
  #pragma unroll
  for (int kt = 0; kt < 4; ++kt){
    bf16x8 af[4], bfr[4];
    #pragma unroll
    for (int i = 0; i < 4; ++i)
      af[i]  = *(const bf16x8*)(qb + (rowbase + row0 + i*16 + lr)*QKVG_ + h*HD_ + kt*32 + kq*8);
    #pragma unroll
    for (int j = 0; j < 4; ++j)
      bfr[j] = *(const bf16x8*)(kb + (rowbase + col0 + j*16 + lr)*QKVG_ + h*HD_ + kt*32 + kq*8);
    #pragma unroll
    for (int i = 0; i < 4; ++i)
      #pragma unroll
      for (int j = 0; j < 4; ++j)
        acc[i][j] = __builtin_amdgcn_mfma_f32_16x16x32_bf16(af[i], bfr[j], acc[i][j], 0, 0, 0);
  }
  #pragma unroll
  for (int i = 0; i < 4; ++i)
    #pragma unroll
    for (int j = 0; j < 4; ++j)
      #pragma unroll
      for (int r = 0; r < 4; ++r){
        int row = row0 + i*16 + kq*4 + r;
        int col = col0 + j*16 + lr;
        int dlt = row - col;
        float f = (dlt >= 0) ? __expf(ld * (float)dlt) : 0.f;
        Ps[swz(row, col)] = f2bf(acc[i][j][r] * f);
      }

  // phase B1: o2 = q @ S_start
  #pragma unroll
  for (int i = 0; i < 4; ++i)
    #pragma unroll
    for (int j = 0; j < 4; ++j) acc[i][j] = zero;
  const uint16_t* Sb = StT + (((size_t)ic*B_ + b)*H_ + h)*(size_t)(HD_*HD_);
  #pragma unroll
  for (int kt = 0; kt < 4; ++kt){
    bf16x8 af[4], bfr[4];
    #pragma unroll
    for (int i = 0; i < 4; ++i)
      af[i]  = *(const bf16x8*)(qb + (rowbase + row0 + i*16 + lr)*QKVG_ + h*HD_ + kt*32 + kq*8);
    #pragma unroll
    for (int j = 0; j < 4; ++j)
      bfr[j] = *(const bf16x8*)(Sb + (size_t)(col0 + j*16 + lr)*HD_ + kt*32 + kq*8);
    #pragma unroll
    for (int i = 0; i < 4; ++i)
      #pragma unroll
      for (int j = 0; j < 4; ++j)
        acc[i][j] = __builtin_amdgcn_mfma_f32_16x16x32_bf16(af[i], bfr[j], acc[i][j], 0, 0, 0);
  }
  #pragma unroll
  for (int i = 0; i < 4; ++i)
    #pragma unroll
    for (int r = 0; r < 4; ++r){
      float dqv = __expf(ld * (float)(row0 + i*16 + kq*4 + r + 1));
      #pragma unroll
      for (int j = 0; j < 4; ++j) acc[i][j][r] *= dqv;
    }

  __syncthreads();

  // phase B2: o += P @ v
  #pragma unroll
  for (int kt = 0; kt < 4; ++kt){
    bf16x8 af[4], bfr[4];
    #pragma unroll
    for (int i = 0; i < 4; ++i)
      af[i]  = *(const bf16x8*)(Ps + swz(row0 + i*16 + lr, kt*32 + kq*8));
    #pragma unroll
    for (int j = 0; j < 4; ++j)
      bfr[j] = *(const bf16x8*)(vT + swz(col0 + j*16 + lr, kt*32 + kq*8));
    #pragma unroll
    for (int i = 0; i < 4; ++i)
      #pragma unroll
      for (int j = 0; j < 4; ++j)
        acc[i][j] = __builtin_amdgcn_mfma_f32_16x16x32_bf16(af[i], bfr[j], acc[i][j], 0, 0, 0);
  }

  #pragma unroll
  for (int i = 0; i < 4; ++i)
    #pragma unroll
    for (int j = 0; j < 4; ++j)
      #pragma unroll
      for (int r = 0; r < 4; ++r){
        int row = row0 + i*16 + kq*4 + r;
        int col = col0 + j*16 + lr;
        o_attn[(rowbase + row)*D_ + h*HD_ + col] = acc[i][j][r];
      }
}

// --------------------------------------------- gate ⊙ + rmsnorm + cast bf16
__global__ __launch_bounds__(256)
void gate_norm_kernel(const float* __restrict__ o_attn, const uint16_t* __restrict__ qkvg,
                      const float* __restrict__ norm_w, uint16_t* __restrict__ on)
{
  const int row = blockIdx.x;
  const int t = threadIdx.x;
  const int c1 = t*4, c2 = 1024 + t*4;
  const float*    orow = o_attn + (size_t)row*D_;
  const uint16_t* grow = qkvg + (size_t)row*QKVG_ + 3*D_;
  float4  o1 = *(const float4*)(orow + c1);
  float4  o2 = *(const float4*)(orow + c2);
  ushort4 g1 = *(const ushort4*)(grow + c1);
  ushort4 g2 = *(const ushort4*)(grow + c2);
  float v[8];
  v[0] = o1.x*bf2f(g1.x); v[1] = o1.y*bf2f(g1.y); v[2] = o1.z*bf2f(g1.z); v[3] = o1.w*bf2f(g1.w);
  v[4] = o2.x*bf2f(g2.x); v[5] = o2.y*bf2f(g2.y); v[6] = o2.z*bf2f(g2.z); v[7] = o2.w*bf2f(g2.w);
  float s = 0.f;
  #pragma unroll
  for (int k = 0; k < 8; ++k) s += v[k]*v[k];
  #pragma unroll
  for (int off = 32; off > 0; off >>= 1) s += __shfl_down(s, off);
  __shared__ float red[4];
  if ((t & 63) == 0) red[t >> 6] = s;
  __syncthreads();
  float total = red[0] + red[1] + red[2] + red[3];
  float scale = rsqrtf(total * (1.f/(float)D_) + 1e-6f);
  float4 w1 = *(const float4*)(norm_w + c1);
  float4 w2 = *(const float4*)(norm_w + c2);
  ushort4 b1, b2;
  b1.x = f2bf(v[0]*scale*w1.x); b1.y = f2bf(v[1]*scale*w1.y);
  b1.z = f2bf(v[2]*scale*w1.z); b1.w = f2bf(v[3]*scale*w1.w);
  b2.x = f2bf(v[4]*scale*w2.x); b2.y = f2bf(v[5]*scale*w2.y);
  b2.z = f2bf(v[6]*scale*w2.z); b2.w = f2bf(v[7]*scale*w2.w);
  *(ushort4*)(on + (size_t)row*D_ + c1) = b1;
  *(ushort4*)(on + (size_t)row*D_ + c2) = b2;
}

// =============================================================== launch
extern "C" void kernel_launch(void* const* d_in, const int* in_sizes, int n_in,
                              void* d_out, int out_size, void* d_ws, size_t ws_size,
                              hipStream_t stream) {
  const float* x         = (const float*)d_in[0];
  const float* log_decay = (const float*)d_in[1];
  const float* Wq        = (const float*)d_in[2];
  const float* Wk        = (const float*)d_in[3];
  const float* Wv        = (const float*)d_in[4];
  const float* Wo        = (const float*)d_in[5];
  const float* Wg1       = (const float*)d_in[6];
  const float* Wg2       = (const float*)d_in[7];
  const float* norm_w    = (const float*)d_in[8];
  float* out = (float*)d_out;

  // workspace layout (~160 MB with aliasing)
  uint8_t* p = (uint8_t*)d_ws;
  uint16_t* xb    = (uint16_t*)p; p += (size_t)M_*D_*2;        // reused as `on`
  uint16_t* WT    = (uint16_t*)p; p += (size_t)QKVG_*D_*2;     // reused as o_att
  uint16_t* WoT   = (uint16_t*)p; p += (size_t)D_*D_*2;
  uint16_t* Wg1b  = (uint16_t*)p; p += (size_t)D_*HD_*2;
  uint16_t* Wg2T  = (uint16_t*)p; p += (size_t)D_*HD_*2;
  uint16_t* qkvg  = (uint16_t*)p; p += (size_t)M_*QKVG_*2;     // reused as Wo partials
  uint16_t* MsumT = (uint16_t*)p; p += (size_t)NC_*B_*H_*HD_*HD_*2;
  uint16_t* StT   = (uint16_t*)p; p += (size_t)NC_*B_*H_*HD_*HD_*2;
  float*    o_att = (float*)WT;
  uint16_t* on    = xb;
  float*    part  = (float*)qkvg;   // 2 x 32MB fp32 partials (qkvg dead by then)

  // 1. cast x + all weight prep (one launch)
  cast_kernel<<<(M_*D_)/1024, 256, 0, stream>>>(x, xb);
  prep_weights<<<dim3(64, 64, 6), 256, 0, stream>>>(Wq, Wk, Wv, Wo, Wg2, Wg1,
                                                    WT, WoT, Wg2T, Wg1b);

  // 2. Wg^T = (Wg1 @ Wg2)^T into WT slice 3
  gemm_bt2<0,1><<<dim3(D_/128, D_/128, 1), 256, 0, stream>>>(
      Wg2T, Wg1b, WT + (size_t)3*D_*D_, D_, D_, HD_, HD_);

  // 3. fused projection: [q|k|v|gate] = act(x @ [Wq|Wk|Wv|Wg])
  gemm_bt2<3,1><<<dim3(QKVG_/128, M_/128, 1), 256, 0, stream>>>(
      xb, WT, qkvg, M_, QKVG_, D_, D_);

  // 4. attention: chunk states -> scan -> intra-chunk
  chunk_state_kernel<<<dim3(H_, B_, NC_), 256, 0, stream>>>(qkvg, log_decay, MsumT);
  scan_kernel<<<dim3(H_, B_, 8), 256, 0, stream>>>(MsumT, log_decay, StT);
  attn_kernel<<<dim3(H_, B_, NC_), 256, 0, stream>>>(qkvg, StT, log_decay, o_att);

  // 5. gate + rmsnorm + final projection (split-K=2)
  gate_norm_kernel<<<M_, 256, 0, stream>>>(o_att, qkvg, norm_w, on);
  gemm_bt2<0,0><<<dim3(D_/128, M_/128, 2), 256, 0, stream>>>(
      on, WoT, part, M_, D_, D_, D_/2);
  add_kernel<<<(M_*D_)/1024, 256, 0, stream>>>(part, part + (size_t)M_*D_, out);
}